// Round 3
// baseline (606.121 us; speedup 1.0000x reference)
//
#include <hip/hip_runtime.h>

typedef unsigned short u16;
typedef unsigned int u32;
typedef __attribute__((ext_vector_type(8))) __bf16 bh8;
typedef __attribute__((ext_vector_type(4))) float fx4;

#define AS1 __attribute__((address_space(1)))
#define AS3 __attribute__((address_space(3)))

__device__ __forceinline__ void gll16(const void* g, void* l) {
  void* gg = const_cast<void*>(g);
  __builtin_amdgcn_global_load_lds((AS1 void*)gg, (AS3 void*)l, 16, 0, 0);
}

__device__ __forceinline__ u16 f2b(float f) {
  union { float f; u32 u; } v; v.f = f;
  u32 r = v.u + 0x7FFFu + ((v.u >> 16) & 1u);
  return (u16)(r >> 16);
}

__device__ __forceinline__ fx4 fzero() { fx4 z = {0.f, 0.f, 0.f, 0.f}; return z; }

#define MFMA16(a, b, c) __builtin_amdgcn_mfma_f32_16x16x32_bf16(a, b, c, 0, 0, 0)

// ---------------- cast f32 -> bf16, vectorized ----------------
__global__ void k_cast(const float* __restrict__ in, u16* __restrict__ out, int n4) {
  int i = blockIdx.x * blockDim.x + threadIdx.x;
  if (i >= n4) return;
  float4 v = reinterpret_cast<const float4*>(in)[i];
  ushort4 o;
  o.x = f2b(v.x); o.y = f2b(v.y); o.z = f2b(v.z); o.w = f2b(v.w);
  reinterpret_cast<ushort4*>(out)[i] = o;
}

// ---------------- transpose + cast: W[R][C] f32 -> Wt[C][R] bf16 ----------------
__global__ void k_transpose_cast(const float* __restrict__ in, u16* __restrict__ out,
                                 int R, int C) {
  __shared__ float t[32][33];
  int tx = threadIdx.x, ty = threadIdx.y;
  int r0 = blockIdx.y * 32, c0 = blockIdx.x * 32;
#pragma unroll
  for (int j = 0; j < 4; j++)
    t[ty + 8 * j][tx] = in[(size_t)(r0 + ty + 8 * j) * C + c0 + tx];
  __syncthreads();
#pragma unroll
  for (int j = 0; j < 4; j++)
    out[(size_t)(c0 + ty + 8 * j) * R + r0 + tx] = f2b(t[tx][ty + 8 * j]);
}

// ---------------- transpose V (bf16): [(b*2048+s)*512 + kv*128 + d] -> [(z*128+d)*2048 + s]
__global__ void k_transpose_v(const u16* __restrict__ in, u16* __restrict__ out) {
  __shared__ u16 t[32][33];
  int tx = threadIdx.x, ty = threadIdx.y;
  int s0 = blockIdx.x * 32, d0 = blockIdx.y * 32;
  int z = blockIdx.z, b = z >> 2, kv = z & 3;
#pragma unroll
  for (int j = 0; j < 4; j++)
    t[ty + 8 * j][tx] = in[(size_t)(b * 2048 + s0 + ty + 8 * j) * 512 + kv * 128 + d0 + tx];
  __syncthreads();
#pragma unroll
  for (int j = 0; j < 4; j++)
    out[(size_t)(z * 128 + d0 + ty + 8 * j) * 2048 + s0 + tx] = t[tx][ty + 8 * j];
}

// ---------------- GEMM core: C[128x128 tile] = A[M][2048] * Bt[N][2048]^T ----------------
__device__ __forceinline__ void gemm_core(const u16* __restrict__ A, const u16* __restrict__ Bt,
                                          int bm, int bn, u16* As, u16* Bs, fx4 acc[4][4]) {
  const int tid = threadIdx.x;
  const int lane = tid & 63, w = tid >> 6;
  const int wr = w >> 1, wc = w & 1;
  const int i = lane & 15, g = lane >> 4;
  const int c0 = tid, c1 = tid + 256;
  const u16* ga0 = A + (size_t)(bm + (c0 >> 2)) * 2048 + (c0 & 3) * 8;
  const u16* ga1 = A + (size_t)(bm + (c1 >> 2)) * 2048 + (c1 & 3) * 8;
  const u16* gb0 = Bt + (size_t)(bn + (c0 >> 2)) * 2048 + (c0 & 3) * 8;
  const u16* gb1 = Bt + (size_t)(bn + (c1 >> 2)) * 2048 + (c1 & 3) * 8;
  u16* la0 = As + c0 * 8; u16* la1 = As + c1 * 8;
  u16* lb0 = Bs + c0 * 8; u16* lb1 = Bs + c1 * 8;
  const u16* ra = As + (wr * 64 + i) * 32 + g * 8;
  const u16* rb = Bs + (wc * 64 + i) * 32 + g * 8;
  for (int kt = 0; kt < 2048; kt += 32) {
    __syncthreads();
    gll16(ga0 + kt, la0);
    gll16(ga1 + kt, la1);
    gll16(gb0 + kt, lb0);
    gll16(gb1 + kt, lb1);
    __syncthreads();
    bh8 af[4], bfr[4];
#pragma unroll
    for (int m = 0; m < 4; m++) af[m] = *reinterpret_cast<const bh8*>(ra + m * 16 * 32);
#pragma unroll
    for (int n = 0; n < 4; n++) bfr[n] = *reinterpret_cast<const bh8*>(rb + n * 16 * 32);
#pragma unroll
    for (int m = 0; m < 4; m++)
#pragma unroll
      for (int n = 0; n < 4; n++)
        acc[m][n] = MFMA16(af[m], bfr[n], acc[m][n]);
  }
}

// ---------------- fused QKV projection GEMM ----------------
__global__ __launch_bounds__(256, 2) void k_proj(const u16* __restrict__ xb,
                                                 const u16* __restrict__ Wqt,
                                                 const u16* __restrict__ Wkt,
                                                 const u16* __restrict__ Wvt,
                                                 u16* __restrict__ Qb, u16* __restrict__ Kb,
                                                 u16* __restrict__ Vb) {
  __shared__ __align__(16) u16 As[128 * 32];
  __shared__ __align__(16) u16 Bs[128 * 32];
  int by = blockIdx.y;
  const u16* Bt; u16* Cp; int bn, ldc; float alpha;
  if (by < 16)      { Bt = Wqt; Cp = Qb; bn = by * 128;        ldc = 2048; alpha = 0.08838834764831845f; }
  else if (by < 20) { Bt = Wkt; Cp = Kb; bn = (by - 16) * 128; ldc = 512;  alpha = 1.0f; }
  else              { Bt = Wvt; Cp = Vb; bn = (by - 20) * 128; ldc = 512;  alpha = 1.0f; }
  int bm = blockIdx.x * 128;
  fx4 acc[4][4];
#pragma unroll
  for (int m = 0; m < 4; m++)
#pragma unroll
    for (int n = 0; n < 4; n++) acc[m][n] = fzero();
  gemm_core(xb, Bt, bm, bn, As, Bs, acc);
  const int lane = threadIdx.x & 63, w = threadIdx.x >> 6;
  const int wr = w >> 1, wc = w & 1, i = lane & 15, g = lane >> 4;
#pragma unroll
  for (int m = 0; m < 4; m++)
#pragma unroll
    for (int n = 0; n < 4; n++)
#pragma unroll
      for (int r = 0; r < 4; r++) {
        int row = bm + wr * 64 + m * 16 + 4 * g + r;
        int col = bn + wc * 64 + n * 16 + i;
        Cp[(size_t)row * ldc + col] = f2b(acc[m][n][r] * alpha);
      }
}

// ---------------- output GEMM (f32 out) ----------------
__global__ __launch_bounds__(256, 2) void k_gemm_out(const u16* __restrict__ Ob,
                                                     const u16* __restrict__ Wot,
                                                     float* __restrict__ C) {
  __shared__ __align__(16) u16 As[128 * 32];
  __shared__ __align__(16) u16 Bs[128 * 32];
  int bm = blockIdx.x * 128, bn = blockIdx.y * 128;
  fx4 acc[4][4];
#pragma unroll
  for (int m = 0; m < 4; m++)
#pragma unroll
    for (int n = 0; n < 4; n++) acc[m][n] = fzero();
  gemm_core(Ob, Wot, bm, bn, As, Bs, acc);
  const int lane = threadIdx.x & 63, w = threadIdx.x >> 6;
  const int wr = w >> 1, wc = w & 1, i = lane & 15, g = lane >> 4;
#pragma unroll
  for (int m = 0; m < 4; m++)
#pragma unroll
    for (int n = 0; n < 4; n++)
#pragma unroll
      for (int r = 0; r < 4; r++) {
        int row = bm + wr * 64 + m * 16 + 4 * g + r;
        int col = bn + wc * 64 + n * 16 + i;
        C[(size_t)row * 2048 + col] = acc[m][n][r];
      }
}

// ---------------- flash attention v3 (causal, GQA) ----------------
// Paired causal q-tiles: block j handles q-tiles {j, 31-j} (uniform 33
// tile-computes). K/V double-buffered with COMPILE-TIME buffer selection
// (2x-unrolled loop; rule #20: no runtime-indexed register arrays).
// One __syncthreads per kv-tile; its implicit vmcnt(0) drains the prefetch
// issued BEFORE compute. LDS = 72 KB -> 2 blocks/CU.
__global__ __launch_bounds__(256, 2) void k_attn(const u16* __restrict__ Qb,
                                                 const u16* __restrict__ Kb,
                                                 const u16* __restrict__ Vt,
                                                 u16* __restrict__ Ob) {
  __shared__ __align__(16) u16 Ks0[64 * 128], Ks1[64 * 128];
  __shared__ __align__(16) u16 Vs0[128 * 64], Vs1[128 * 64];
  __shared__ __align__(16) u16 Pl[4][16 * 64];
  const int tid = threadIdx.x, lane = tid & 63, w = tid >> 6;
  const int i = lane & 15, g = lane >> 4;
  const int j = blockIdx.x;                 // 0..15
  const int head = blockIdx.y, b = blockIdx.z, kv = head >> 2;
  const int qa = j, qc = 31 - j;
  const int qmin_a = qa * 64 + w * 16, qmin_c = qc * 64 + w * 16;
  const int nt = 32 - j;                    // kv-tiles for qc (superset of qa's)
  const int nta = j + 1;                    // kv-tiles for qa

  const u16* Kbb = Kb + (size_t)b * 2048 * 512 + kv * 128;
  const u16* Vbb = Vt + (size_t)(b * 4 + kv) * 128 * 2048;

  // Q fragments for both q-tiles (pre-scaled in projection)
  bh8 qfa[4], qfc[4];
  {
    const u16* qpa = Qb + (size_t)(b * 2048 + qmin_a + i) * 2048 + head * 128 + g * 8;
    const u16* qpc = Qb + (size_t)(b * 2048 + qmin_c + i) * 2048 + head * 128 + g * 8;
#pragma unroll
    for (int kb = 0; kb < 4; kb++) {
      qfa[kb] = *reinterpret_cast<const bh8*>(qpa + kb * 32);
      qfc[kb] = *reinterpret_cast<const bh8*>(qpc + kb * 32);
    }
  }

  fx4 oa[8], oc[8];
#pragma unroll
  for (int dt = 0; dt < 8; dt++) { oa[dt] = fzero(); oc[dt] = fzero(); }
  float ma[4] = {-1e30f, -1e30f, -1e30f, -1e30f}, la[4] = {0.f, 0.f, 0.f, 0.f};
  float mc[4] = {-1e30f, -1e30f, -1e30f, -1e30f}, lc[4] = {0.f, 0.f, 0.f, 0.f};

  auto STAGE = [&](u16* Kd, u16* Vd, int s0) {
#pragma unroll
    for (int cc = 0; cc < 4; cc++) {
      int c = tid + cc * 256;
      gll16(Kbb + (size_t)(s0 + (c >> 4)) * 512 + (((c & 15) ^ ((c >> 4) & 7)) * 8),
            Kd + c * 8);
      gll16(Vbb + (size_t)(c >> 3) * 2048 + s0 + (((c & 7) ^ ((c >> 3) & 7)) * 8),
            Vd + c * 8);
    }
  };

  auto TILE = [&](const bh8* qf, fx4* o, float* m, float* l, int qmin,
                  const u16* Kbuf, const u16* Vbuf, int s0) {
    fx4 sc[4];
#pragma unroll
    for (int st = 0; st < 4; st++) {
      sc[st] = fzero();
#pragma unroll
      for (int kb = 0; kb < 4; kb++) {
        bh8 kf = *reinterpret_cast<const bh8*>(Kbuf + (st * 16 + i) * 128 +
                                               (((kb * 4 + g) ^ (i & 7)) * 8));
        sc[st] = MFMA16(qf[kb], kf, sc[st]);
      }
    }
    if (s0 + 63 > qmin) {
#pragma unroll
      for (int st = 0; st < 4; st++)
#pragma unroll
        for (int r = 0; r < 4; r++) {
          int s = s0 + st * 16 + i;
          int q = qmin + 4 * g + r;
          if (s > q) sc[st][r] = -1e30f;
        }
    }
    float corr[4];
#pragma unroll
    for (int r = 0; r < 4; r++) {
      float v = fmaxf(fmaxf(sc[0][r], sc[1][r]), fmaxf(sc[2][r], sc[3][r]));
      v = fmaxf(v, __shfl_xor(v, 1));
      v = fmaxf(v, __shfl_xor(v, 2));
      v = fmaxf(v, __shfl_xor(v, 4));
      v = fmaxf(v, __shfl_xor(v, 8));
      float mn = fmaxf(m[r], v);
      corr[r] = __expf(m[r] - mn);
      m[r] = mn;
    }
    float p[4][4];
#pragma unroll
    for (int r = 0; r < 4; r++) {
      float s = 0.f;
#pragma unroll
      for (int st = 0; st < 4; st++) { p[st][r] = __expf(sc[st][r] - m[r]); s += p[st][r]; }
      s += __shfl_xor(s, 1); s += __shfl_xor(s, 2);
      s += __shfl_xor(s, 4); s += __shfl_xor(s, 8);
      l[r] = l[r] * corr[r] + s;
    }
#pragma unroll
    for (int dt = 0; dt < 8; dt++)
#pragma unroll
      for (int r = 0; r < 4; r++) o[dt][r] *= corr[r];

    // P -> per-wave XOR-swizzled LDS (granule cg stored at cg^(row&7))
#pragma unroll
    for (int st = 0; st < 4; st++)
#pragma unroll
      for (int r = 0; r < 4; r++) {
        int row = 4 * g + r;
        int cg = st * 2 + (i >> 3);
        Pl[w][row * 64 + ((cg ^ (row & 7)) << 3) + (i & 7)] = f2b(p[st][r]);
      }
    bh8 pf0 = *reinterpret_cast<const bh8*>(&Pl[w][i * 64 + ((g ^ (i & 7)) << 3)]);
    bh8 pf1 = *reinterpret_cast<const bh8*>(&Pl[w][i * 64 + (((4 + g) ^ (i & 7)) << 3)]);
#pragma unroll
    for (int dt = 0; dt < 8; dt++) {
      bh8 v0 = *reinterpret_cast<const bh8*>(Vbuf + (dt * 16 + i) * 64 +
                                             ((g ^ (i & 7)) * 8));
      bh8 v1 = *reinterpret_cast<const bh8*>(Vbuf + (dt * 16 + i) * 64 +
                                             (((4 + g) ^ (i & 7)) * 8));
      o[dt] = MFMA16(pf0, v0, o[dt]);
      o[dt] = MFMA16(pf1, v1, o[dt]);
    }
  };

  STAGE(Ks0, Vs0, 0);
  __syncthreads();
  for (int t = 0; t < nt; t += 2) {
    // even tile -> buffers 0
    if (t + 1 < nt) STAGE(Ks1, Vs1, (t + 1) * 64);
    TILE(qfc, oc, mc, lc, qmin_c, Ks0, Vs0, t * 64);
    if (t < nta) TILE(qfa, oa, ma, la, qmin_a, Ks0, Vs0, t * 64);
    __syncthreads();
    if (t + 1 >= nt) break;
    // odd tile -> buffers 1
    if (t + 2 < nt) STAGE(Ks0, Vs0, (t + 2) * 64);
    TILE(qfc, oc, mc, lc, qmin_c, Ks1, Vs1, (t + 1) * 64);
    if (t + 1 < nta) TILE(qfa, oa, ma, la, qmin_a, Ks1, Vs1, (t + 1) * 64);
    __syncthreads();
  }

#pragma unroll
  for (int r = 0; r < 4; r++) {
    float inva = 1.0f / la[r];
    float invc = 1.0f / lc[r];
#pragma unroll
    for (int dt = 0; dt < 8; dt++) {
      Ob[(size_t)(b * 2048 + qmin_a + 4 * g + r) * 2048 + head * 128 + dt * 16 + i] =
          f2b(oa[dt][r] * inva);
      Ob[(size_t)(b * 2048 + qmin_c + 4 * g + r) * 2048 + head * 128 + dt * 16 + i] =
          f2b(oc[dt][r] * invc);
    }
  }
}

extern "C" void kernel_launch(void* const* d_in, const int* in_sizes, int n_in,
                              void* d_out, int out_size, void* d_ws, size_t ws_size,
                              hipStream_t stream) {
  (void)in_sizes; (void)n_in; (void)out_size; (void)ws_size;
  const float* x  = (const float*)d_in[0];
  const float* Wq = (const float*)d_in[1];
  const float* Wk = (const float*)d_in[2];
  const float* Wv = (const float*)d_in[3];
  const float* Wo = (const float*)d_in[4];

  char* ws = (char*)d_ws;
  size_t off = 0;
  auto alloc = [&](size_t bytes) {
    void* p = ws + off;
    off += (bytes + 255) & ~(size_t)255;
    return p;
  };
  u16* xb  = (u16*)alloc(8388608ull * 2);  // x bf16; reused as Ob after proj
  u16* Wqt = (u16*)alloc(4194304ull * 2);
  u16* Wkt = (u16*)alloc(1048576ull * 2);
  u16* Wvt = (u16*)alloc(1048576ull * 2);
  u16* Wot = (u16*)alloc(4194304ull * 2);
  u16* Qb  = (u16*)alloc(8388608ull * 2);
  u16* Kb  = (u16*)alloc(2097152ull * 2);
  u16* Vb  = (u16*)alloc(2097152ull * 2);
  u16* Vt  = (u16*)alloc(2097152ull * 2);
  u16* Ob  = xb;  // x is dead after k_proj

  k_cast<<<8192, 256, 0, stream>>>(x, xb, 2097152);
  k_transpose_cast<<<dim3(64, 64), dim3(32, 8), 0, stream>>>(Wq, Wqt, 2048, 2048);
  k_transpose_cast<<<dim3(16, 64), dim3(32, 8), 0, stream>>>(Wk, Wkt, 2048, 512);
  k_transpose_cast<<<dim3(16, 64), dim3(32, 8), 0, stream>>>(Wv, Wvt, 2048, 512);
  k_transpose_cast<<<dim3(64, 64), dim3(32, 8), 0, stream>>>(Wo, Wot, 2048, 2048);
  k_proj<<<dim3(32, 24), 256, 0, stream>>>(xb, Wqt, Wkt, Wvt, Qb, Kb, Vb);
  k_transpose_v<<<dim3(64, 4, 8), dim3(32, 8), 0, stream>>>(Vb, Vt);
  k_attn<<<dim3(16, 16, 2), 256, 0, stream>>>(Qb, Kb, Vt, Ob);
  k_gemm_out<<<dim3(32, 16), 256, 0, stream>>>(Ob, Wot, (float*)d_out);
}

// Round 4
// 343.387 us; speedup vs baseline: 1.7651x; 1.7651x over previous
//
#include <hip/hip_runtime.h>

typedef unsigned short u16;
typedef unsigned int u32;
typedef __attribute__((ext_vector_type(8))) __bf16 bh8;
typedef __attribute__((ext_vector_type(4))) float fx4;

#define AS1 __attribute__((address_space(1)))
#define AS3 __attribute__((address_space(3)))

__device__ __forceinline__ void gll16(const void* g, void* l) {
  void* gg = const_cast<void*>(g);
  __builtin_amdgcn_global_load_lds((AS1 void*)gg, (AS3 void*)l, 16, 0, 0);
}

__device__ __forceinline__ u16 f2b(float f) {
  union { float f; u32 u; } v; v.f = f;
  u32 r = v.u + 0x7FFFu + ((v.u >> 16) & 1u);
  return (u16)(r >> 16);
}

__device__ __forceinline__ fx4 fzero() { fx4 z = {0.f, 0.f, 0.f, 0.f}; return z; }

#define MFMA16(a, b, c) __builtin_amdgcn_mfma_f32_16x16x32_bf16(a, b, c, 0, 0, 0)

// ---------------- cast f32 -> bf16, vectorized ----------------
__global__ void k_cast(const float* __restrict__ in, u16* __restrict__ out, int n4) {
  int i = blockIdx.x * blockDim.x + threadIdx.x;
  if (i >= n4) return;
  float4 v = reinterpret_cast<const float4*>(in)[i];
  ushort4 o;
  o.x = f2b(v.x); o.y = f2b(v.y); o.z = f2b(v.z); o.w = f2b(v.w);
  reinterpret_cast<ushort4*>(out)[i] = o;
}

// ---------------- transpose + cast: W[R][C] f32 -> Wt[C][R] bf16 ----------------
__global__ void k_transpose_cast(const float* __restrict__ in, u16* __restrict__ out,
                                 int R, int C) {
  __shared__ float t[32][33];
  int tx = threadIdx.x, ty = threadIdx.y;
  int r0 = blockIdx.y * 32, c0 = blockIdx.x * 32;
#pragma unroll
  for (int j = 0; j < 4; j++)
    t[ty + 8 * j][tx] = in[(size_t)(r0 + ty + 8 * j) * C + c0 + tx];
  __syncthreads();
#pragma unroll
  for (int j = 0; j < 4; j++)
    out[(size_t)(c0 + ty + 8 * j) * R + r0 + tx] = f2b(t[tx][ty + 8 * j]);
}

// ---------------- transpose V (bf16): [(b*2048+s)*512 + kv*128 + d] -> [(z*128+d)*2048 + s]
__global__ void k_transpose_v(const u16* __restrict__ in, u16* __restrict__ out) {
  __shared__ u16 t[32][33];
  int tx = threadIdx.x, ty = threadIdx.y;
  int s0 = blockIdx.x * 32, d0 = blockIdx.y * 32;
  int z = blockIdx.z, b = z >> 2, kv = z & 3;
#pragma unroll
  for (int j = 0; j < 4; j++)
    t[ty + 8 * j][tx] = in[(size_t)(b * 2048 + s0 + ty + 8 * j) * 512 + kv * 128 + d0 + tx];
  __syncthreads();
#pragma unroll
  for (int j = 0; j < 4; j++)
    out[(size_t)(z * 128 + d0 + ty + 8 * j) * 2048 + s0 + tx] = t[tx][ty + 8 * j];
}

// ---------------- GEMM core: C[128x128 tile] = A[M][2048] * Bt[N][2048]^T ----------------
__device__ __forceinline__ void gemm_core(const u16* __restrict__ A, const u16* __restrict__ Bt,
                                          int bm, int bn, u16* As, u16* Bs, fx4 acc[4][4]) {
  const int tid = threadIdx.x;
  const int lane = tid & 63, w = tid >> 6;
  const int wr = w >> 1, wc = w & 1;
  const int i = lane & 15, g = lane >> 4;
  const int c0 = tid, c1 = tid + 256;
  const u16* ga0 = A + (size_t)(bm + (c0 >> 2)) * 2048 + (c0 & 3) * 8;
  const u16* ga1 = A + (size_t)(bm + (c1 >> 2)) * 2048 + (c1 & 3) * 8;
  const u16* gb0 = Bt + (size_t)(bn + (c0 >> 2)) * 2048 + (c0 & 3) * 8;
  const u16* gb1 = Bt + (size_t)(bn + (c1 >> 2)) * 2048 + (c1 & 3) * 8;
  u16* la0 = As + c0 * 8; u16* la1 = As + c1 * 8;
  u16* lb0 = Bs + c0 * 8; u16* lb1 = Bs + c1 * 8;
  const u16* ra = As + (wr * 64 + i) * 32 + g * 8;
  const u16* rb = Bs + (wc * 64 + i) * 32 + g * 8;
  for (int kt = 0; kt < 2048; kt += 32) {
    __syncthreads();
    gll16(ga0 + kt, la0);
    gll16(ga1 + kt, la1);
    gll16(gb0 + kt, lb0);
    gll16(gb1 + kt, lb1);
    __syncthreads();
    bh8 af[4], bfr[4];
#pragma unroll
    for (int m = 0; m < 4; m++) af[m] = *reinterpret_cast<const bh8*>(ra + m * 16 * 32);
#pragma unroll
    for (int n = 0; n < 4; n++) bfr[n] = *reinterpret_cast<const bh8*>(rb + n * 16 * 32);
#pragma unroll
    for (int m = 0; m < 4; m++)
#pragma unroll
      for (int n = 0; n < 4; n++)
        acc[m][n] = MFMA16(af[m], bfr[n], acc[m][n]);
  }
}

// ---------------- fused QKV projection GEMM ----------------
__global__ __launch_bounds__(256, 2) void k_proj(const u16* __restrict__ xb,
                                                 const u16* __restrict__ Wqt,
                                                 const u16* __restrict__ Wkt,
                                                 const u16* __restrict__ Wvt,
                                                 u16* __restrict__ Qb, u16* __restrict__ Kb,
                                                 u16* __restrict__ Vb) {
  __shared__ __align__(16) u16 As[128 * 32];
  __shared__ __align__(16) u16 Bs[128 * 32];
  int by = blockIdx.y;
  const u16* Bt; u16* Cp; int bn, ldc; float alpha;
  if (by < 16)      { Bt = Wqt; Cp = Qb; bn = by * 128;        ldc = 2048; alpha = 0.08838834764831845f; }
  else if (by < 20) { Bt = Wkt; Cp = Kb; bn = (by - 16) * 128; ldc = 512;  alpha = 1.0f; }
  else              { Bt = Wvt; Cp = Vb; bn = (by - 20) * 128; ldc = 512;  alpha = 1.0f; }
  int bm = blockIdx.x * 128;
  fx4 acc[4][4];
#pragma unroll
  for (int m = 0; m < 4; m++)
#pragma unroll
    for (int n = 0; n < 4; n++) acc[m][n] = fzero();
  gemm_core(xb, Bt, bm, bn, As, Bs, acc);
  const int lane = threadIdx.x & 63, w = threadIdx.x >> 6;
  const int wr = w >> 1, wc = w & 1, i = lane & 15, g = lane >> 4;
#pragma unroll
  for (int m = 0; m < 4; m++)
#pragma unroll
    for (int n = 0; n < 4; n++)
#pragma unroll
      for (int r = 0; r < 4; r++) {
        int row = bm + wr * 64 + m * 16 + 4 * g + r;
        int col = bn + wc * 64 + n * 16 + i;
        Cp[(size_t)row * ldc + col] = f2b(acc[m][n][r] * alpha);
      }
}

// ---------------- output GEMM (f32 out) ----------------
__global__ __launch_bounds__(256, 2) void k_gemm_out(const u16* __restrict__ Ob,
                                                     const u16* __restrict__ Wot,
                                                     float* __restrict__ C) {
  __shared__ __align__(16) u16 As[128 * 32];
  __shared__ __align__(16) u16 Bs[128 * 32];
  int bm = blockIdx.x * 128, bn = blockIdx.y * 128;
  fx4 acc[4][4];
#pragma unroll
  for (int m = 0; m < 4; m++)
#pragma unroll
    for (int n = 0; n < 4; n++) acc[m][n] = fzero();
  gemm_core(Ob, Wot, bm, bn, As, Bs, acc);
  const int lane = threadIdx.x & 63, w = threadIdx.x >> 6;
  const int wr = w >> 1, wc = w & 1, i = lane & 15, g = lane >> 4;
#pragma unroll
  for (int m = 0; m < 4; m++)
#pragma unroll
    for (int n = 0; n < 4; n++)
#pragma unroll
      for (int r = 0; r < 4; r++) {
        int row = bm + wr * 64 + m * 16 + 4 * g + r;
        int col = bn + wc * 64 + n * 16 + i;
        C[(size_t)row * 2048 + col] = acc[m][n][r];
      }
}

// ---------------- flash attention v4 (causal, GQA) ----------------
// 512 threads = 8 waves. Wave-split causal pairing: waves 0-3 own q-tile
// 31-j (16 rows each), waves 4-7 own q-tile j. Each wave carries ONE
// accumulator set (~round-1 register footprint -> no spills). K/V staged
// once per kv-tile, shared by all waves; double-buffered with static
// buffer selection. LDS 80KB -> 2 blocks/CU (16 waves/CU).
__global__ __launch_bounds__(512, 4) void k_attn(const u16* __restrict__ Qb,
                                                 const u16* __restrict__ Kb,
                                                 const u16* __restrict__ Vt,
                                                 u16* __restrict__ Ob) {
  __shared__ __align__(16) u16 Ks0[64 * 128], Ks1[64 * 128];
  __shared__ __align__(16) u16 Vs0[128 * 64], Vs1[128 * 64];
  __shared__ __align__(16) u16 Pl[8][16 * 64];
  const int tid = threadIdx.x, lane = tid & 63, w = tid >> 6;
  const int i = lane & 15, g = lane >> 4;
  const int j = blockIdx.x;                 // 0..15
  const int head = blockIdx.y, b = blockIdx.z, kv = head >> 2;
  const bool isA = (w >= 4);                // waves 4-7: early tile j
  const int qt = isA ? j : (31 - j);
  const int qmin = qt * 64 + (w & 3) * 16;  // this wave's 16 q-rows
  const int nt = 32 - j;                    // block iteration count
  const int myNt = isA ? (j + 1) : nt;      // kv-tiles this wave consumes

  const u16* Kbb = Kb + (size_t)b * 2048 * 512 + kv * 128;
  const u16* Vbb = Vt + (size_t)(b * 4 + kv) * 128 * 2048;

  // Q fragments (pre-scaled by 1/sqrt(128) in the projection)
  bh8 qf[4];
  {
    const u16* qp = Qb + (size_t)(b * 2048 + qmin + i) * 2048 + head * 128 + g * 8;
#pragma unroll
    for (int kb = 0; kb < 4; kb++) qf[kb] = *reinterpret_cast<const bh8*>(qp + kb * 32);
  }

  fx4 o[8];
#pragma unroll
  for (int dt = 0; dt < 8; dt++) o[dt] = fzero();
  float m[4] = {-1e30f, -1e30f, -1e30f, -1e30f};
  float l[4] = {0.f, 0.f, 0.f, 0.f};

  auto STAGE = [&](u16* Kd, u16* Vd, int s0) {
#pragma unroll
    for (int cc = 0; cc < 2; cc++) {
      int c = tid + cc * 512;
      gll16(Kbb + (size_t)(s0 + (c >> 4)) * 512 + (((c & 15) ^ ((c >> 4) & 7)) * 8),
            Kd + c * 8);
      gll16(Vbb + (size_t)(c >> 3) * 2048 + s0 + (((c & 7) ^ ((c >> 3) & 7)) * 8),
            Vd + c * 8);
    }
  };

  auto TILE = [&](const u16* Kbuf, const u16* Vbuf, int s0) {
    fx4 sc[4];
#pragma unroll
    for (int st = 0; st < 4; st++) {
      sc[st] = fzero();
#pragma unroll
      for (int kb = 0; kb < 4; kb++) {
        bh8 kf = *reinterpret_cast<const bh8*>(Kbuf + (st * 16 + i) * 128 +
                                               (((kb * 4 + g) ^ (i & 7)) * 8));
        sc[st] = MFMA16(qf[kb], kf, sc[st]);
      }
    }
    if (s0 + 63 > qmin) {
#pragma unroll
      for (int st = 0; st < 4; st++)
#pragma unroll
        for (int r = 0; r < 4; r++) {
          int s = s0 + st * 16 + i;
          int q = qmin + 4 * g + r;
          if (s > q) sc[st][r] = -1e30f;
        }
    }
    float corr[4];
#pragma unroll
    for (int r = 0; r < 4; r++) {
      float v = fmaxf(fmaxf(sc[0][r], sc[1][r]), fmaxf(sc[2][r], sc[3][r]));
      v = fmaxf(v, __shfl_xor(v, 1));
      v = fmaxf(v, __shfl_xor(v, 2));
      v = fmaxf(v, __shfl_xor(v, 4));
      v = fmaxf(v, __shfl_xor(v, 8));
      float mn = fmaxf(m[r], v);
      corr[r] = __expf(m[r] - mn);
      m[r] = mn;
    }
    float p[4][4];
#pragma unroll
    for (int r = 0; r < 4; r++) {
      float s = 0.f;
#pragma unroll
      for (int st = 0; st < 4; st++) { p[st][r] = __expf(sc[st][r] - m[r]); s += p[st][r]; }
      s += __shfl_xor(s, 1); s += __shfl_xor(s, 2);
      s += __shfl_xor(s, 4); s += __shfl_xor(s, 8);
      l[r] = l[r] * corr[r] + s;
    }
#pragma unroll
    for (int dt = 0; dt < 8; dt++)
#pragma unroll
      for (int r = 0; r < 4; r++) o[dt][r] *= corr[r];

    // P -> per-wave XOR-swizzled LDS (granule cg stored at cg^(row&7));
    // in-wave write->read, no barrier needed.
#pragma unroll
    for (int st = 0; st < 4; st++)
#pragma unroll
      for (int r = 0; r < 4; r++) {
        int row = 4 * g + r;
        int cg = st * 2 + (i >> 3);
        Pl[w][row * 64 + ((cg ^ (row & 7)) << 3) + (i & 7)] = f2b(p[st][r]);
      }
    bh8 pf0 = *reinterpret_cast<const bh8*>(&Pl[w][i * 64 + ((g ^ (i & 7)) << 3)]);
    bh8 pf1 = *reinterpret_cast<const bh8*>(&Pl[w][i * 64 + (((4 + g) ^ (i & 7)) << 3)]);
#pragma unroll
    for (int dt = 0; dt < 8; dt++) {
      bh8 v0 = *reinterpret_cast<const bh8*>(Vbuf + (dt * 16 + i) * 64 +
                                             ((g ^ (i & 7)) * 8));
      bh8 v1 = *reinterpret_cast<const bh8*>(Vbuf + (dt * 16 + i) * 64 +
                                             (((4 + g) ^ (i & 7)) * 8));
      o[dt] = MFMA16(pf0, v0, o[dt]);
      o[dt] = MFMA16(pf1, v1, o[dt]);
    }
  };

  STAGE(Ks0, Vs0, 0);
  __syncthreads();
  for (int t = 0; t < nt; t += 2) {
    // even tile -> buffers 0
    if (t + 1 < nt) STAGE(Ks1, Vs1, (t + 1) * 64);
    if (t < myNt) TILE(Ks0, Vs0, t * 64);
    __syncthreads();
    if (t + 1 >= nt) break;
    // odd tile -> buffers 1
    if (t + 2 < nt) STAGE(Ks0, Vs0, (t + 2) * 64);
    if (t + 1 < myNt) TILE(Ks1, Vs1, (t + 1) * 64);
    __syncthreads();
  }

#pragma unroll
  for (int r = 0; r < 4; r++) {
    float inv = 1.0f / l[r];
#pragma unroll
    for (int dt = 0; dt < 8; dt++)
      Ob[(size_t)(b * 2048 + qmin + 4 * g + r) * 2048 + head * 128 + dt * 16 + i] =
          f2b(o[dt][r] * inv);
  }
}

extern "C" void kernel_launch(void* const* d_in, const int* in_sizes, int n_in,
                              void* d_out, int out_size, void* d_ws, size_t ws_size,
                              hipStream_t stream) {
  (void)in_sizes; (void)n_in; (void)out_size; (void)ws_size;
  const float* x  = (const float*)d_in[0];
  const float* Wq = (const float*)d_in[1];
  const float* Wk = (const float*)d_in[2];
  const float* Wv = (const float*)d_in[3];
  const float* Wo = (const float*)d_in[4];

  char* ws = (char*)d_ws;
  size_t off = 0;
  auto alloc = [&](size_t bytes) {
    void* p = ws + off;
    off += (bytes + 255) & ~(size_t)255;
    return p;
  };
  u16* xb  = (u16*)alloc(8388608ull * 2);  // x bf16; reused as Ob after proj
  u16* Wqt = (u16*)alloc(4194304ull * 2);
  u16* Wkt = (u16*)alloc(1048576ull * 2);
  u16* Wvt = (u16*)alloc(1048576ull * 2);
  u16* Wot = (u16*)alloc(4194304ull * 2);
  u16* Qb  = (u16*)alloc(8388608ull * 2);
  u16* Kb  = (u16*)alloc(2097152ull * 2);
  u16* Vb  = (u16*)alloc(2097152ull * 2);
  u16* Vt  = (u16*)alloc(2097152ull * 2);
  u16* Ob  = xb;  // x is dead after k_proj

  k_cast<<<8192, 256, 0, stream>>>(x, xb, 2097152);
  k_transpose_cast<<<dim3(64, 64), dim3(32, 8), 0, stream>>>(Wq, Wqt, 2048, 2048);
  k_transpose_cast<<<dim3(16, 64), dim3(32, 8), 0, stream>>>(Wk, Wkt, 2048, 512);
  k_transpose_cast<<<dim3(16, 64), dim3(32, 8), 0, stream>>>(Wv, Wvt, 2048, 512);
  k_transpose_cast<<<dim3(64, 64), dim3(32, 8), 0, stream>>>(Wo, Wot, 2048, 2048);
  k_proj<<<dim3(32, 24), 256, 0, stream>>>(xb, Wqt, Wkt, Wvt, Qb, Kb, Vb);
  k_transpose_v<<<dim3(64, 4, 8), dim3(32, 8), 0, stream>>>(Vb, Vt);
  k_attn<<<dim3(16, 16, 2), 512, 0, stream>>>(Qb, Kb, Vt, Ob);
  k_gemm_out<<<dim3(32, 16), 256, 0, stream>>>(Ob, Wot, (float*)d_out);
}

// Round 5
// 329.955 us; speedup vs baseline: 1.8370x; 1.0407x over previous
//
#include <hip/hip_runtime.h>

typedef unsigned short u16;
typedef unsigned int u32;
typedef __attribute__((ext_vector_type(8))) __bf16 bh8;
typedef __attribute__((ext_vector_type(4))) float fx4;

#define AS1 __attribute__((address_space(1)))
#define AS3 __attribute__((address_space(3)))

__device__ __forceinline__ void gll16(const void* g, void* l) {
  void* gg = const_cast<void*>(g);
  __builtin_amdgcn_global_load_lds((AS1 void*)gg, (AS3 void*)l, 16, 0, 0);
}

__device__ __forceinline__ u16 f2b(float f) {
  union { float f; u32 u; } v; v.f = f;
  u32 r = v.u + 0x7FFFu + ((v.u >> 16) & 1u);
  return (u16)(r >> 16);
}

__device__ __forceinline__ fx4 fzero() { fx4 z = {0.f, 0.f, 0.f, 0.f}; return z; }

#define MFMA16(a, b, c) __builtin_amdgcn_mfma_f32_16x16x32_bf16(a, b, c, 0, 0, 0)

// ---------------- cast f32 -> bf16, vectorized ----------------
__global__ void k_cast(const float* __restrict__ in, u16* __restrict__ out, int n4) {
  int i = blockIdx.x * blockDim.x + threadIdx.x;
  if (i >= n4) return;
  float4 v = reinterpret_cast<const float4*>(in)[i];
  ushort4 o;
  o.x = f2b(v.x); o.y = f2b(v.y); o.z = f2b(v.z); o.w = f2b(v.w);
  reinterpret_cast<ushort4*>(out)[i] = o;
}

// ---------------- transpose + cast: W[R][C] f32 -> Wt[C][R] bf16 ----------------
__global__ void k_transpose_cast(const float* __restrict__ in, u16* __restrict__ out,
                                 int R, int C) {
  __shared__ float t[32][33];
  int tx = threadIdx.x, ty = threadIdx.y;
  int r0 = blockIdx.y * 32, c0 = blockIdx.x * 32;
#pragma unroll
  for (int j = 0; j < 4; j++)
    t[ty + 8 * j][tx] = in[(size_t)(r0 + ty + 8 * j) * C + c0 + tx];
  __syncthreads();
#pragma unroll
  for (int j = 0; j < 4; j++)
    out[(size_t)(c0 + ty + 8 * j) * R + r0 + tx] = f2b(t[tx][ty + 8 * j]);
}

// ---------------- transpose V (bf16): [(b*2048+s)*512 + kv*128 + d] -> [(z*128+d)*2048 + s]
__global__ void k_transpose_v(const u16* __restrict__ in, u16* __restrict__ out) {
  __shared__ u16 t[32][33];
  int tx = threadIdx.x, ty = threadIdx.y;
  int s0 = blockIdx.x * 32, d0 = blockIdx.y * 32;
  int z = blockIdx.z, b = z >> 2, kv = z & 3;
#pragma unroll
  for (int j = 0; j < 4; j++)
    t[ty + 8 * j][tx] = in[(size_t)(b * 2048 + s0 + ty + 8 * j) * 512 + kv * 128 + d0 + tx];
  __syncthreads();
#pragma unroll
  for (int j = 0; j < 4; j++)
    out[(size_t)(z * 128 + d0 + ty + 8 * j) * 2048 + s0 + tx] = t[tx][ty + 8 * j];
}

// ---------------- GEMM core: C[128x128 tile] = A[M][2048] * Bt[N][2048]^T ----------------
__device__ __forceinline__ void gemm_core(const u16* __restrict__ A, const u16* __restrict__ Bt,
                                          int bm, int bn, u16* As, u16* Bs, fx4 acc[4][4]) {
  const int tid = threadIdx.x;
  const int lane = tid & 63, w = tid >> 6;
  const int wr = w >> 1, wc = w & 1;
  const int i = lane & 15, g = lane >> 4;
  const int c0 = tid, c1 = tid + 256;
  const u16* ga0 = A + (size_t)(bm + (c0 >> 2)) * 2048 + (c0 & 3) * 8;
  const u16* ga1 = A + (size_t)(bm + (c1 >> 2)) * 2048 + (c1 & 3) * 8;
  const u16* gb0 = Bt + (size_t)(bn + (c0 >> 2)) * 2048 + (c0 & 3) * 8;
  const u16* gb1 = Bt + (size_t)(bn + (c1 >> 2)) * 2048 + (c1 & 3) * 8;
  u16* la0 = As + c0 * 8; u16* la1 = As + c1 * 8;
  u16* lb0 = Bs + c0 * 8; u16* lb1 = Bs + c1 * 8;
  const u16* ra = As + (wr * 64 + i) * 32 + g * 8;
  const u16* rb = Bs + (wc * 64 + i) * 32 + g * 8;
  for (int kt = 0; kt < 2048; kt += 32) {
    __syncthreads();
    gll16(ga0 + kt, la0);
    gll16(ga1 + kt, la1);
    gll16(gb0 + kt, lb0);
    gll16(gb1 + kt, lb1);
    __syncthreads();
    bh8 af[4], bfr[4];
#pragma unroll
    for (int m = 0; m < 4; m++) af[m] = *reinterpret_cast<const bh8*>(ra + m * 16 * 32);
#pragma unroll
    for (int n = 0; n < 4; n++) bfr[n] = *reinterpret_cast<const bh8*>(rb + n * 16 * 32);
#pragma unroll
    for (int m = 0; m < 4; m++)
#pragma unroll
      for (int n = 0; n < 4; n++)
        acc[m][n] = MFMA16(af[m], bfr[n], acc[m][n]);
  }
}

// ---------------- fused QKV projection GEMM ----------------
__global__ __launch_bounds__(256, 3) void k_proj(const u16* __restrict__ xb,
                                                 const u16* __restrict__ Wqt,
                                                 const u16* __restrict__ Wkt,
                                                 const u16* __restrict__ Wvt,
                                                 u16* __restrict__ Qb, u16* __restrict__ Kb,
                                                 u16* __restrict__ Vb) {
  __shared__ __align__(16) u16 As[128 * 32];
  __shared__ __align__(16) u16 Bs[128 * 32];
  int by = blockIdx.y;
  const u16* Bt; u16* Cp; int bn, ldc; float alpha;
  if (by < 16)      { Bt = Wqt; Cp = Qb; bn = by * 128;        ldc = 2048; alpha = 0.08838834764831845f; }
  else if (by < 20) { Bt = Wkt; Cp = Kb; bn = (by - 16) * 128; ldc = 512;  alpha = 1.0f; }
  else              { Bt = Wvt; Cp = Vb; bn = (by - 20) * 128; ldc = 512;  alpha = 1.0f; }
  int bm = blockIdx.x * 128;
  fx4 acc[4][4];
#pragma unroll
  for (int m = 0; m < 4; m++)
#pragma unroll
    for (int n = 0; n < 4; n++) acc[m][n] = fzero();
  gemm_core(xb, Bt, bm, bn, As, Bs, acc);
  const int lane = threadIdx.x & 63, w = threadIdx.x >> 6;
  const int wr = w >> 1, wc = w & 1, i = lane & 15, g = lane >> 4;
#pragma unroll
  for (int m = 0; m < 4; m++)
#pragma unroll
    for (int n = 0; n < 4; n++)
#pragma unroll
      for (int r = 0; r < 4; r++) {
        int row = bm + wr * 64 + m * 16 + 4 * g + r;
        int col = bn + wc * 64 + n * 16 + i;
        Cp[(size_t)row * ldc + col] = f2b(acc[m][n][r] * alpha);
      }
}

// ---------------- output GEMM (f32 out) ----------------
__global__ __launch_bounds__(256, 3) void k_gemm_out(const u16* __restrict__ Ob,
                                                     const u16* __restrict__ Wot,
                                                     float* __restrict__ C) {
  __shared__ __align__(16) u16 As[128 * 32];
  __shared__ __align__(16) u16 Bs[128 * 32];
  int bm = blockIdx.x * 128, bn = blockIdx.y * 128;
  fx4 acc[4][4];
#pragma unroll
  for (int m = 0; m < 4; m++)
#pragma unroll
    for (int n = 0; n < 4; n++) acc[m][n] = fzero();
  gemm_core(Ob, Wot, bm, bn, As, Bs, acc);
  const int lane = threadIdx.x & 63, w = threadIdx.x >> 6;
  const int wr = w >> 1, wc = w & 1, i = lane & 15, g = lane >> 4;
#pragma unroll
  for (int m = 0; m < 4; m++)
#pragma unroll
    for (int n = 0; n < 4; n++)
#pragma unroll
      for (int r = 0; r < 4; r++) {
        int row = bm + wr * 64 + m * 16 + 4 * g + r;
        int col = bn + wc * 64 + n * 16 + i;
        C[(size_t)row * 2048 + col] = acc[m][n][r];
      }
}

// ---------------- flash attention v5 (causal, GQA) ----------------
// v4 structure (8 waves, wave-split causal pairing, K/V double-buffered,
// static buffer selection) + this round: lazy-l (epilogue-only reduction),
// defer-max rescale (T13, THR=8), s_setprio around MFMA clusters (T5).
__global__ __launch_bounds__(512, 4) void k_attn(const u16* __restrict__ Qb,
                                                 const u16* __restrict__ Kb,
                                                 const u16* __restrict__ Vt,
                                                 u16* __restrict__ Ob) {
  __shared__ __align__(16) u16 Ks0[64 * 128], Ks1[64 * 128];
  __shared__ __align__(16) u16 Vs0[128 * 64], Vs1[128 * 64];
  __shared__ __align__(16) u16 Pl[8][16 * 64];
  const int tid = threadIdx.x, lane = tid & 63, w = tid >> 6;
  const int i = lane & 15, g = lane >> 4;
  const int j = blockIdx.x;                 // 0..15
  const int head = blockIdx.y, b = blockIdx.z, kv = head >> 2;
  const bool isA = (w >= 4);                // waves 4-7: early tile j
  const int qt = isA ? j : (31 - j);
  const int qmin = qt * 64 + (w & 3) * 16;  // this wave's 16 q-rows
  const int nt = 32 - j;                    // block iteration count
  const int myNt = isA ? (j + 1) : nt;      // kv-tiles this wave consumes

  const u16* Kbb = Kb + (size_t)b * 2048 * 512 + kv * 128;
  const u16* Vbb = Vt + (size_t)(b * 4 + kv) * 128 * 2048;

  // Q fragments (pre-scaled by 1/sqrt(128) in the projection)
  bh8 qf[4];
  {
    const u16* qp = Qb + (size_t)(b * 2048 + qmin + i) * 2048 + head * 128 + g * 8;
#pragma unroll
    for (int kb = 0; kb < 4; kb++) qf[kb] = *reinterpret_cast<const bh8*>(qp + kb * 32);
  }

  fx4 o[8];
#pragma unroll
  for (int dt = 0; dt < 8; dt++) o[dt] = fzero();
  float m[4] = {-1e30f, -1e30f, -1e30f, -1e30f};
  float lp[4] = {0.f, 0.f, 0.f, 0.f};       // per-lane PARTIAL row sums

  auto STAGE = [&](u16* Kd, u16* Vd, int s0) {
#pragma unroll
    for (int cc = 0; cc < 2; cc++) {
      int c = tid + cc * 512;
      gll16(Kbb + (size_t)(s0 + (c >> 4)) * 512 + (((c & 15) ^ ((c >> 4) & 7)) * 8),
            Kd + c * 8);
      gll16(Vbb + (size_t)(c >> 3) * 2048 + s0 + (((c & 7) ^ ((c >> 3) & 7)) * 8),
            Vd + c * 8);
    }
  };

  auto TILE = [&](const u16* Kbuf, const u16* Vbuf, int s0) {
    fx4 sc[4];
    __builtin_amdgcn_s_setprio(1);
#pragma unroll
    for (int st = 0; st < 4; st++) {
      sc[st] = fzero();
#pragma unroll
      for (int kb = 0; kb < 4; kb++) {
        bh8 kf = *reinterpret_cast<const bh8*>(Kbuf + (st * 16 + i) * 128 +
                                               (((kb * 4 + g) ^ (i & 7)) * 8));
        sc[st] = MFMA16(qf[kb], kf, sc[st]);
      }
    }
    __builtin_amdgcn_s_setprio(0);
    if (s0 + 63 > qmin) {
#pragma unroll
      for (int st = 0; st < 4; st++)
#pragma unroll
        for (int r = 0; r < 4; r++) {
          int s = s0 + st * 16 + i;
          int q = qmin + 4 * g + r;
          if (s > q) sc[st][r] = -1e30f;
        }
    }
    // tile row max (cross the 16 lanes sharing g)
    float pmax[4];
#pragma unroll
    for (int r = 0; r < 4; r++) {
      float v = fmaxf(fmaxf(sc[0][r], sc[1][r]), fmaxf(sc[2][r], sc[3][r]));
      v = fmaxf(v, __shfl_xor(v, 1));
      v = fmaxf(v, __shfl_xor(v, 2));
      v = fmaxf(v, __shfl_xor(v, 4));
      v = fmaxf(v, __shfl_xor(v, 8));
      pmax[r] = v;
    }
    // defer-max: only rescale when some row grew past m + 8 (wave-uniform)
    int need = 0;
#pragma unroll
    for (int r = 0; r < 4; r++) need |= (pmax[r] > m[r] + 8.0f) ? 1 : 0;
    if (__any(need)) {
#pragma unroll
      for (int r = 0; r < 4; r++) {
        float mn = fmaxf(m[r], pmax[r]);
        float corr = __expf(m[r] - mn);
        m[r] = mn;
        lp[r] *= corr;
#pragma unroll
        for (int dt = 0; dt < 8; dt++) o[dt][r] *= corr;
      }
    }
    float p[4][4];
#pragma unroll
    for (int r = 0; r < 4; r++) {
#pragma unroll
      for (int st = 0; st < 4; st++) p[st][r] = __expf(sc[st][r] - m[r]);
      lp[r] += (p[0][r] + p[1][r]) + (p[2][r] + p[3][r]);
    }

    // P -> per-wave XOR-swizzled LDS (granule cg stored at cg^(row&7));
    // in-wave write->read, no barrier needed.
#pragma unroll
    for (int st = 0; st < 4; st++)
#pragma unroll
      for (int r = 0; r < 4; r++) {
        int row = 4 * g + r;
        int cg = st * 2 + (i >> 3);
        Pl[w][row * 64 + ((cg ^ (row & 7)) << 3) + (i & 7)] = f2b(p[st][r]);
      }
    bh8 pf0 = *reinterpret_cast<const bh8*>(&Pl[w][i * 64 + ((g ^ (i & 7)) << 3)]);
    bh8 pf1 = *reinterpret_cast<const bh8*>(&Pl[w][i * 64 + (((4 + g) ^ (i & 7)) << 3)]);
    __builtin_amdgcn_s_setprio(1);
#pragma unroll
    for (int dt = 0; dt < 8; dt++) {
      bh8 v0 = *reinterpret_cast<const bh8*>(Vbuf + (dt * 16 + i) * 64 +
                                             ((g ^ (i & 7)) * 8));
      bh8 v1 = *reinterpret_cast<const bh8*>(Vbuf + (dt * 16 + i) * 64 +
                                             (((4 + g) ^ (i & 7)) * 8));
      o[dt] = MFMA16(pf0, v0, o[dt]);
      o[dt] = MFMA16(pf1, v1, o[dt]);
    }
    __builtin_amdgcn_s_setprio(0);
  };

  STAGE(Ks0, Vs0, 0);
  __syncthreads();
  for (int t = 0; t < nt; t += 2) {
    // even tile -> buffers 0
    if (t + 1 < nt) STAGE(Ks1, Vs1, (t + 1) * 64);
    if (t < myNt) TILE(Ks0, Vs0, t * 64);
    __syncthreads();
    if (t + 1 >= nt) break;
    // odd tile -> buffers 1
    if (t + 2 < nt) STAGE(Ks0, Vs0, (t + 2) * 64);
    if (t + 1 < myNt) TILE(Ks1, Vs1, (t + 1) * 64);
    __syncthreads();
  }

  // epilogue: reduce the lazy row-sum partials once, normalize, store
#pragma unroll
  for (int r = 0; r < 4; r++) {
    float s = lp[r];
    s += __shfl_xor(s, 1);
    s += __shfl_xor(s, 2);
    s += __shfl_xor(s, 4);
    s += __shfl_xor(s, 8);
    float inv = 1.0f / s;
#pragma unroll
    for (int dt = 0; dt < 8; dt++)
      Ob[(size_t)(b * 2048 + qmin + 4 * g + r) * 2048 + head * 128 + dt * 16 + i] =
          f2b(o[dt][r] * inv);
  }
}

extern "C" void kernel_launch(void* const* d_in, const int* in_sizes, int n_in,
                              void* d_out, int out_size, void* d_ws, size_t ws_size,
                              hipStream_t stream) {
  (void)in_sizes; (void)n_in; (void)out_size; (void)ws_size;
  const float* x  = (const float*)d_in[0];
  const float* Wq = (const float*)d_in[1];
  const float* Wk = (const float*)d_in[2];
  const float* Wv = (const float*)d_in[3];
  const float* Wo = (const float*)d_in[4];

  char* ws = (char*)d_ws;
  size_t off = 0;
  auto alloc = [&](size_t bytes) {
    void* p = ws + off;
    off += (bytes + 255) & ~(size_t)255;
    return p;
  };
  u16* xb  = (u16*)alloc(8388608ull * 2);  // x bf16; reused as Ob after proj
  u16* Wqt = (u16*)alloc(4194304ull * 2);
  u16* Wkt = (u16*)alloc(1048576ull * 2);
  u16* Wvt = (u16*)alloc(1048576ull * 2);
  u16* Wot = (u16*)alloc(4194304ull * 2);
  u16* Qb  = (u16*)alloc(8388608ull * 2);
  u16* Kb  = (u16*)alloc(2097152ull * 2);
  u16* Vb  = (u16*)alloc(2097152ull * 2);
  u16* Vt  = (u16*)alloc(2097152ull * 2);
  u16* Ob  = xb;  // x is dead after k_proj

  k_cast<<<8192, 256, 0, stream>>>(x, xb, 2097152);
  k_transpose_cast<<<dim3(64, 64), dim3(32, 8), 0, stream>>>(Wq, Wqt, 2048, 2048);
  k_transpose_cast<<<dim3(16, 64), dim3(32, 8), 0, stream>>>(Wk, Wkt, 2048, 512);
  k_transpose_cast<<<dim3(16, 64), dim3(32, 8), 0, stream>>>(Wv, Wvt, 2048, 512);
  k_transpose_cast<<<dim3(64, 64), dim3(32, 8), 0, stream>>>(Wo, Wot, 2048, 2048);
  k_proj<<<dim3(32, 24), 256, 0, stream>>>(xb, Wqt, Wkt, Wvt, Qb, Kb, Vb);
  k_transpose_v<<<dim3(64, 4, 8), dim3(32, 8), 0, stream>>>(Vb, Vt);
  k_attn<<<dim3(16, 16, 2), 512, 0, stream>>>(Qb, Kb, Vt, Ob);
  k_gemm_out<<<dim3(32, 16), 256, 0, stream>>>(Ob, Wot, (float*)d_out);
}

// Round 6
// 323.050 us; speedup vs baseline: 1.8762x; 1.0214x over previous
//
#include <hip/hip_runtime.h>

typedef unsigned short u16;
typedef unsigned int u32;
typedef __attribute__((ext_vector_type(8))) __bf16 bh8;
typedef __attribute__((ext_vector_type(4))) float fx4;

#define AS1 __attribute__((address_space(1)))
#define AS3 __attribute__((address_space(3)))

__device__ __forceinline__ void gll16(const void* g, void* l) {
  void* gg = const_cast<void*>(g);
  __builtin_amdgcn_global_load_lds((AS1 void*)gg, (AS3 void*)l, 16, 0, 0);
}

__device__ __forceinline__ u16 f2b(float f) {
  union { float f; u32 u; } v; v.f = f;
  u32 r = v.u + 0x7FFFu + ((v.u >> 16) & 1u);
  return (u16)(r >> 16);
}

__device__ __forceinline__ fx4 fzero() { fx4 z = {0.f, 0.f, 0.f, 0.f}; return z; }

#define MFMA16(a, b, c) __builtin_amdgcn_mfma_f32_16x16x32_bf16(a, b, c, 0, 0, 0)

// ---------------- cast f32 -> bf16, vectorized ----------------
__global__ void k_cast(const float* __restrict__ in, u16* __restrict__ out, int n4) {
  int i = blockIdx.x * blockDim.x + threadIdx.x;
  if (i >= n4) return;
  float4 v = reinterpret_cast<const float4*>(in)[i];
  ushort4 o;
  o.x = f2b(v.x); o.y = f2b(v.y); o.z = f2b(v.z); o.w = f2b(v.w);
  reinterpret_cast<ushort4*>(out)[i] = o;
}

// ---------------- transpose + cast: W[R][C] f32 -> Wt[C][R] bf16 ----------------
__global__ void k_transpose_cast(const float* __restrict__ in, u16* __restrict__ out,
                                 int R, int C) {
  __shared__ float t[32][33];
  int tx = threadIdx.x, ty = threadIdx.y;
  int r0 = blockIdx.y * 32, c0 = blockIdx.x * 32;
#pragma unroll
  for (int j = 0; j < 4; j++)
    t[ty + 8 * j][tx] = in[(size_t)(r0 + ty + 8 * j) * C + c0 + tx];
  __syncthreads();
#pragma unroll
  for (int j = 0; j < 4; j++)
    out[(size_t)(c0 + ty + 8 * j) * R + r0 + tx] = f2b(t[tx][ty + 8 * j]);
}

// ---------------- transpose V (bf16): [(b*2048+s)*512 + kv*128 + d] -> [(z*128+d)*2048 + s]
__global__ void k_transpose_v(const u16* __restrict__ in, u16* __restrict__ out) {
  __shared__ u16 t[32][33];
  int tx = threadIdx.x, ty = threadIdx.y;
  int s0 = blockIdx.x * 32, d0 = blockIdx.y * 32;
  int z = blockIdx.z, b = z >> 2, kv = z & 3;
#pragma unroll
  for (int j = 0; j < 4; j++)
    t[ty + 8 * j][tx] = in[(size_t)(b * 2048 + s0 + ty + 8 * j) * 512 + kv * 128 + d0 + tx];
  __syncthreads();
#pragma unroll
  for (int j = 0; j < 4; j++)
    out[(size_t)(z * 128 + d0 + ty + 8 * j) * 2048 + s0 + tx] = t[tx][ty + 8 * j];
}

// ---------------- 256x256 GEMM core (8 waves, BK=64, dbuf LDS, swizzled) ----
// Sm: 65536 u16 = 128 KB. A/B tiles [2 buf][256 rows][64 cols] bf16, each row
// 8 granules of 16B; granule lg of row r stored at physical pg = lg ^ (r&7),
// achieved by pre-swizzling the GLOBAL source (gll16 dest must stay linear).
// Per K-tile: 4 phases x {A-frag ds_reads + 16 MFMA}; B-frags loaded once;
// next tile's 4 half-tiles staged in phases 0-1; one __syncthreads per tile.
__device__ __forceinline__ void gemm256(const u16* __restrict__ A, const u16* __restrict__ Bt,
                                        int bm, int bn, u16* Sm, fx4 (&acc)[8][4]) {
  u16* As = Sm;            // [2][16384]
  u16* Bs = Sm + 32768;    // [2][16384]
  const int tid = threadIdx.x;
  const int lane = tid & 63;
  const int i = lane & 15, g = lane >> 4;
  const int w = tid >> 6;
  const int wr = w >> 2, wc = w & 3;    // 2 (M) x 4 (N) waves
  const int arow0 = wr * 128 + i;
  const int brow0 = wc * 64 + i;
  const int swz = i & 7;

  auto SHALF = [&](const u16* G, int grow0, u16* Ld, int kt) {
#pragma unroll
    for (int cc = 0; cc < 2; cc++) {
      int p = tid + cc * 512;           // physical granule 0..1023 (128 rows x 8)
      int row = p >> 3;
      int lg = (p & 7) ^ (row & 7);     // logical granule for this slot
      gll16(G + (size_t)(grow0 + row) * 2048 + kt + lg * 8, Ld + p * 8);
    }
  };

  auto ITER = [&](const u16* cA, const u16* cB, u16* nA, u16* nB, int ktn, bool st) {
    bh8 bf[4][2];
#pragma unroll
    for (int nf = 0; nf < 4; nf++)
#pragma unroll
      for (int kk = 0; kk < 2; kk++)
        bf[nf][kk] = *reinterpret_cast<const bh8*>(
            cB + (brow0 + nf * 16) * 64 + (((kk * 4 + g) ^ swz) << 3));
#pragma unroll
    for (int mp = 0; mp < 4; mp++) {
      if (st && mp == 0) { SHALF(A, bm, nA, ktn); SHALF(Bt, bn, nB, ktn); }
      if (st && mp == 1) { SHALF(A, bm + 128, nA + 8192, ktn); SHALF(Bt, bn + 128, nB + 8192, ktn); }
      bh8 af[2][2];
#pragma unroll
      for (int mm = 0; mm < 2; mm++)
#pragma unroll
        for (int kk = 0; kk < 2; kk++)
          af[mm][kk] = *reinterpret_cast<const bh8*>(
              cA + (arow0 + (mp * 2 + mm) * 16) * 64 + (((kk * 4 + g) ^ swz) << 3));
      __builtin_amdgcn_s_setprio(1);
#pragma unroll
      for (int mm = 0; mm < 2; mm++)
#pragma unroll
        for (int nf = 0; nf < 4; nf++)
#pragma unroll
          for (int kk = 0; kk < 2; kk++)
            acc[mp * 2 + mm][nf] = MFMA16(af[mm][kk], bf[nf][kk], acc[mp * 2 + mm][nf]);
      __builtin_amdgcn_s_setprio(0);
    }
  };

  // prologue: stage tile 0 into buffer 0
  SHALF(A, bm, As, 0); SHALF(A, bm + 128, As + 8192, 0);
  SHALF(Bt, bn, Bs, 0); SHALF(Bt, bn + 128, Bs + 8192, 0);
  __syncthreads();
  // 32 K-tiles, 2x unrolled for static buffer parity
  for (int t = 0; t < 32; t += 2) {
    ITER(As, Bs, As + 16384, Bs + 16384, (t + 1) * 64, true);
    __syncthreads();
    ITER(As + 16384, Bs + 16384, As, Bs, (t + 2) * 64, t + 2 < 32);
    __syncthreads();
  }
}

// ---------------- fused QKV projection GEMM (256x256 tiles) ----------------
// Wt = concatenated [3072][2048] (Wq^T rows 0-2047, Wk^T 2048-2559, Wv^T 2560-3071).
__global__ __launch_bounds__(512, 2) void k_proj(const u16* __restrict__ xb,
                                                 const u16* __restrict__ Wt,
                                                 u16* __restrict__ Qb, u16* __restrict__ Kb,
                                                 u16* __restrict__ Vb) {
  __shared__ __align__(16) u16 Sm[65536];
  fx4 acc[8][4];
#pragma unroll
  for (int m = 0; m < 8; m++)
#pragma unroll
    for (int n = 0; n < 4; n++) acc[m][n] = fzero();
  const int bm = blockIdx.x * 256, by = blockIdx.y, bn = by * 256;
  gemm256(xb, Wt, bm, bn, Sm, acc);

  u16* Cp; int coff, ldc; float alpha;
  if (by < 8)       { Cp = Qb; coff = by * 256;        ldc = 2048; alpha = 0.08838834764831845f; }
  else if (by < 10) { Cp = Kb; coff = (by - 8) * 256;  ldc = 512;  alpha = 1.0f; }
  else              { Cp = Vb; coff = (by - 10) * 256; ldc = 512;  alpha = 1.0f; }

  const int lane = threadIdx.x & 63, w = threadIdx.x >> 6;
  const int wr = w >> 2, wc = w & 3, i = lane & 15, g = lane >> 4;
#pragma unroll
  for (int mf = 0; mf < 8; mf++)
#pragma unroll
    for (int nf = 0; nf < 4; nf++)
#pragma unroll
      for (int r = 0; r < 4; r++) {
        int row = bm + wr * 128 + mf * 16 + 4 * g + r;
        int col = coff + wc * 64 + nf * 16 + i;
        Cp[(size_t)row * ldc + col] = f2b(acc[mf][nf][r] * alpha);
      }
}

// ---------------- output GEMM (f32 out, 256x256 tiles) ----------------
__global__ __launch_bounds__(512, 2) void k_gemm_out(const u16* __restrict__ Ob,
                                                     const u16* __restrict__ Wot,
                                                     float* __restrict__ C) {
  __shared__ __align__(16) u16 Sm[65536];
  fx4 acc[8][4];
#pragma unroll
  for (int m = 0; m < 8; m++)
#pragma unroll
    for (int n = 0; n < 4; n++) acc[m][n] = fzero();
  const int bm = blockIdx.x * 256, bn = blockIdx.y * 256;
  gemm256(Ob, Wot, bm, bn, Sm, acc);

  const int lane = threadIdx.x & 63, w = threadIdx.x >> 6;
  const int wr = w >> 2, wc = w & 3, i = lane & 15, g = lane >> 4;
#pragma unroll
  for (int mf = 0; mf < 8; mf++)
#pragma unroll
    for (int nf = 0; nf < 4; nf++)
#pragma unroll
      for (int r = 0; r < 4; r++) {
        int row = bm + wr * 128 + mf * 16 + 4 * g + r;
        int col = bn + wc * 64 + nf * 16 + i;
        C[(size_t)row * 2048 + col] = acc[mf][nf][r];
      }
}

// ---------------- flash attention v5 (causal, GQA) — unchanged ----------------
__global__ __launch_bounds__(512, 4) void k_attn(const u16* __restrict__ Qb,
                                                 const u16* __restrict__ Kb,
                                                 const u16* __restrict__ Vt,
                                                 u16* __restrict__ Ob) {
  __shared__ __align__(16) u16 Ks0[64 * 128], Ks1[64 * 128];
  __shared__ __align__(16) u16 Vs0[128 * 64], Vs1[128 * 64];
  __shared__ __align__(16) u16 Pl[8][16 * 64];
  const int tid = threadIdx.x, lane = tid & 63, w = tid >> 6;
  const int i = lane & 15, g = lane >> 4;
  const int j = blockIdx.x;                 // 0..15
  const int head = blockIdx.y, b = blockIdx.z, kv = head >> 2;
  const bool isA = (w >= 4);                // waves 4-7: early tile j
  const int qt = isA ? j : (31 - j);
  const int qmin = qt * 64 + (w & 3) * 16;  // this wave's 16 q-rows
  const int nt = 32 - j;                    // block iteration count
  const int myNt = isA ? (j + 1) : nt;      // kv-tiles this wave consumes

  const u16* Kbb = Kb + (size_t)b * 2048 * 512 + kv * 128;
  const u16* Vbb = Vt + (size_t)(b * 4 + kv) * 128 * 2048;

  bh8 qf[4];
  {
    const u16* qp = Qb + (size_t)(b * 2048 + qmin + i) * 2048 + head * 128 + g * 8;
#pragma unroll
    for (int kb = 0; kb < 4; kb++) qf[kb] = *reinterpret_cast<const bh8*>(qp + kb * 32);
  }

  fx4 o[8];
#pragma unroll
  for (int dt = 0; dt < 8; dt++) o[dt] = fzero();
  float m[4] = {-1e30f, -1e30f, -1e30f, -1e30f};
  float lp[4] = {0.f, 0.f, 0.f, 0.f};       // per-lane PARTIAL row sums

  auto STAGE = [&](u16* Kd, u16* Vd, int s0) {
#pragma unroll
    for (int cc = 0; cc < 2; cc++) {
      int c = tid + cc * 512;
      gll16(Kbb + (size_t)(s0 + (c >> 4)) * 512 + (((c & 15) ^ ((c >> 4) & 7)) * 8),
            Kd + c * 8);
      gll16(Vbb + (size_t)(c >> 3) * 2048 + s0 + (((c & 7) ^ ((c >> 3) & 7)) * 8),
            Vd + c * 8);
    }
  };

  auto TILE = [&](const u16* Kbuf, const u16* Vbuf, int s0) {
    fx4 sc[4];
    __builtin_amdgcn_s_setprio(1);
#pragma unroll
    for (int st = 0; st < 4; st++) {
      sc[st] = fzero();
#pragma unroll
      for (int kb = 0; kb < 4; kb++) {
        bh8 kf = *reinterpret_cast<const bh8*>(Kbuf + (st * 16 + i) * 128 +
                                               (((kb * 4 + g) ^ (i & 7)) * 8));
        sc[st] = MFMA16(qf[kb], kf, sc[st]);
      }
    }
    __builtin_amdgcn_s_setprio(0);
    if (s0 + 63 > qmin) {
#pragma unroll
      for (int st = 0; st < 4; st++)
#pragma unroll
        for (int r = 0; r < 4; r++) {
          int s = s0 + st * 16 + i;
          int q = qmin + 4 * g + r;
          if (s > q) sc[st][r] = -1e30f;
        }
    }
    float pmax[4];
#pragma unroll
    for (int r = 0; r < 4; r++) {
      float v = fmaxf(fmaxf(sc[0][r], sc[1][r]), fmaxf(sc[2][r], sc[3][r]));
      v = fmaxf(v, __shfl_xor(v, 1));
      v = fmaxf(v, __shfl_xor(v, 2));
      v = fmaxf(v, __shfl_xor(v, 4));
      v = fmaxf(v, __shfl_xor(v, 8));
      pmax[r] = v;
    }
    int need = 0;
#pragma unroll
    for (int r = 0; r < 4; r++) need |= (pmax[r] > m[r] + 8.0f) ? 1 : 0;
    if (__any(need)) {
#pragma unroll
      for (int r = 0; r < 4; r++) {
        float mn = fmaxf(m[r], pmax[r]);
        float corr = __expf(m[r] - mn);
        m[r] = mn;
        lp[r] *= corr;
#pragma unroll
        for (int dt = 0; dt < 8; dt++) o[dt][r] *= corr;
      }
    }
    float p[4][4];
#pragma unroll
    for (int r = 0; r < 4; r++) {
#pragma unroll
      for (int st = 0; st < 4; st++) p[st][r] = __expf(sc[st][r] - m[r]);
      lp[r] += (p[0][r] + p[1][r]) + (p[2][r] + p[3][r]);
    }

#pragma unroll
    for (int st = 0; st < 4; st++)
#pragma unroll
      for (int r = 0; r < 4; r++) {
        int row = 4 * g + r;
        int cg = st * 2 + (i >> 3);
        Pl[w][row * 64 + ((cg ^ (row & 7)) << 3) + (i & 7)] = f2b(p[st][r]);
      }
    bh8 pf0 = *reinterpret_cast<const bh8*>(&Pl[w][i * 64 + ((g ^ (i & 7)) << 3)]);
    bh8 pf1 = *reinterpret_cast<const bh8*>(&Pl[w][i * 64 + (((4 + g) ^ (i & 7)) << 3)]);
    __builtin_amdgcn_s_setprio(1);
#pragma unroll
    for (int dt = 0; dt < 8; dt++) {
      bh8 v0 = *reinterpret_cast<const bh8*>(Vbuf + (dt * 16 + i) * 64 +
                                             ((g ^ (i & 7)) * 8));
      bh8 v1 = *reinterpret_cast<const bh8*>(Vbuf + (dt * 16 + i) * 64 +
                                             (((4 + g) ^ (i & 7)) * 8));
      o[dt] = MFMA16(pf0, v0, o[dt]);
      o[dt] = MFMA16(pf1, v1, o[dt]);
    }
    __builtin_amdgcn_s_setprio(0);
  };

  STAGE(Ks0, Vs0, 0);
  __syncthreads();
  for (int t = 0; t < nt; t += 2) {
    if (t + 1 < nt) STAGE(Ks1, Vs1, (t + 1) * 64);
    if (t < myNt) TILE(Ks0, Vs0, t * 64);
    __syncthreads();
    if (t + 1 >= nt) break;
    if (t + 2 < nt) STAGE(Ks0, Vs0, (t + 2) * 64);
    if (t + 1 < myNt) TILE(Ks1, Vs1, (t + 1) * 64);
    __syncthreads();
  }

#pragma unroll
  for (int r = 0; r < 4; r++) {
    float s = lp[r];
    s += __shfl_xor(s, 1);
    s += __shfl_xor(s, 2);
    s += __shfl_xor(s, 4);
    s += __shfl_xor(s, 8);
    float inv = 1.0f / s;
#pragma unroll
    for (int dt = 0; dt < 8; dt++)
      Ob[(size_t)(b * 2048 + qmin + 4 * g + r) * 2048 + head * 128 + dt * 16 + i] =
          f2b(o[dt][r] * inv);
  }
}

extern "C" void kernel_launch(void* const* d_in, const int* in_sizes, int n_in,
                              void* d_out, int out_size, void* d_ws, size_t ws_size,
                              hipStream_t stream) {
  (void)in_sizes; (void)n_in; (void)out_size; (void)ws_size;
  const float* x  = (const float*)d_in[0];
  const float* Wq = (const float*)d_in[1];
  const float* Wk = (const float*)d_in[2];
  const float* Wv = (const float*)d_in[3];
  const float* Wo = (const float*)d_in[4];

  char* ws = (char*)d_ws;
  size_t off = 0;
  auto alloc = [&](size_t bytes) {
    void* p = ws + off;
    off += (bytes + 255) & ~(size_t)255;
    return p;
  };
  u16* xb  = (u16*)alloc(8388608ull * 2);  // x bf16; reused as Ob after proj
  u16* Wqt = (u16*)alloc(4194304ull * 2);  // rows 0-2047 of concat Wt
  u16* Wkt = (u16*)alloc(1048576ull * 2);  // rows 2048-2559 (contiguous)
  u16* Wvt = (u16*)alloc(1048576ull * 2);  // rows 2560-3071 (contiguous)
  u16* Wot = (u16*)alloc(4194304ull * 2);
  u16* Qb  = (u16*)alloc(8388608ull * 2);
  u16* Kb  = (u16*)alloc(2097152ull * 2);
  u16* Vb  = (u16*)alloc(2097152ull * 2);
  u16* Vt  = (u16*)alloc(2097152ull * 2);
  u16* Ob  = xb;  // x is dead after k_proj

  k_cast<<<8192, 256, 0, stream>>>(x, xb, 2097152);
  k_transpose_cast<<<dim3(64, 64), dim3(32, 8), 0, stream>>>(Wq, Wqt, 2048, 2048);
  k_transpose_cast<<<dim3(16, 64), dim3(32, 8), 0, stream>>>(Wk, Wkt, 2048, 512);
  k_transpose_cast<<<dim3(16, 64), dim3(32, 8), 0, stream>>>(Wv, Wvt, 2048, 512);
  k_transpose_cast<<<dim3(64, 64), dim3(32, 8), 0, stream>>>(Wo, Wot, 2048, 2048);
  k_proj<<<dim3(16, 12), 512, 0, stream>>>(xb, Wqt, Qb, Kb, Vb);
  k_transpose_v<<<dim3(64, 4, 8), dim3(32, 8), 0, stream>>>(Vb, Vt);
  k_attn<<<dim3(16, 16, 2), 512, 0, stream>>>(Qb, Kb, Vt, Ob);
  k_gemm_out<<<dim3(16, 8), 512, 0, stream>>>(Ob, Wot, (float*)d_out);
}